// Round 5
// baseline (336.210 us; speedup 1.0000x reference)
//
#include <hip/hip_runtime.h>
#include <cstdint>
#include <cstddef>

// Problem constants: B=4,S=2048,D=1024,E=32,H=128,K=2
#define NTOK 8192
#define DIM  1024
#define NEXP 32
#define NH   128
#define TT   32               // tokens per FFN tile
#define SLOTS 16              // tile slots per (expert,choice); grid-stride
#define LCAP2 512             // per-(expert,choice) capacity (mean 256)
#define RT   32               // tokens per router block

typedef __attribute__((ext_vector_type(8))) short short8;
typedef __attribute__((ext_vector_type(4))) short short4_;
typedef __attribute__((ext_vector_type(4))) float float4_;

static __device__ __forceinline__ unsigned short f2bf(float f) {
  unsigned u = __float_as_uint(f);
  return (unsigned short)((u + 0x7fffu + ((u >> 16) & 1u)) >> 16);
}
static __device__ __forceinline__ float bf2f(unsigned short h) {
  return __uint_as_float(((unsigned)h) << 16);
}

// ------------- K1: fused prep (transposes + x->bf16) + router --------------
// grid 12544: [0,4096) wk [E][D][H]->[E][H][D] bf16; [4096,8192) wv -> [E][D][H];
//             [8192,12288) x fp32->bf16; [12288,12544) router (256 blocks).
__global__ __launch_bounds__(256) void prep_router_kernel(
    const float* __restrict__ w_keys, const float* __restrict__ w_values,
    const float* __restrict__ x, const float* __restrict__ w_sel,
    unsigned short* __restrict__ wk_t, unsigned short* __restrict__ wv_t,
    unsigned short* __restrict__ xbf,
    int* __restrict__ counts, unsigned* __restrict__ list)
{
  __shared__ float tile[32][33];
  __shared__ __align__(16) float xs_t[64][36];
  __shared__ float ws[NEXP][65];
  __shared__ float S[RT][33];

  const int bid = blockIdx.x;
  const int tid = threadIdx.x;

  if (bid < 8192) {
    // ---- weight transpose + convert
    const float* src; unsigned short* dst; int R, C, lb;
    if (bid < 4096) { src = w_keys;   dst = wk_t; R = DIM; C = NH;  lb = bid; }
    else            { src = w_values; dst = wv_t; R = NH;  C = DIM; lb = bid - 4096; }
    const int e  = lb >> 7;
    const int t  = lb & 127;
    const int tpc = C >> 5;
    const int r0 = (t / tpc) * 32;
    const int c0 = (t % tpc) * 32;
    const float* s = src + (size_t)e * R * C;
    unsigned short* d = dst + (size_t)e * R * C;

    const int i = tid >> 3;
    const int j = (tid & 7) * 4;
    float4 v = *(const float4*)(s + (size_t)(r0 + i) * C + c0 + j);
    tile[i][j] = v.x; tile[i][j + 1] = v.y; tile[i][j + 2] = v.z; tile[i][j + 3] = v.w;
    __syncthreads();
    unsigned lo = (unsigned)f2bf(tile[j + 0][i]) | ((unsigned)f2bf(tile[j + 1][i]) << 16);
    unsigned hi = (unsigned)f2bf(tile[j + 2][i]) | ((unsigned)f2bf(tile[j + 3][i]) << 16);
    uint2 u; u.x = lo; u.y = hi;
    *(uint2*)(d + (size_t)(c0 + i) * R + r0 + j) = u;
  } else if (bid < 12288) {
    // ---- x fp32 -> bf16
    const int lb = bid - 8192;
    size_t i = ((size_t)lb * 256 + tid) * 8;
    float4 a = *(const float4*)(x + i);
    float4 b = *(const float4*)(x + i + 4);
    uint4 u;
    u.x = (unsigned)f2bf(a.x) | ((unsigned)f2bf(a.y) << 16);
    u.y = (unsigned)f2bf(a.z) | ((unsigned)f2bf(a.w) << 16);
    u.z = (unsigned)f2bf(b.x) | ((unsigned)f2bf(b.y) << 16);
    u.w = (unsigned)f2bf(b.z) | ((unsigned)f2bf(b.w) << 16);
    *(uint4*)(xbf + i) = u;
  } else {
    // ---- router: fp32 logits, top-2, per-(expert,choice) lists
    const int tok0 = (bid - 12288) * RT;
    const int tr   = tid >> 3;
    const int d8   = (tid & 7) * 8;
    const int tg4  = (tid & 7) * 4;

    float acc[4] = {0.f, 0.f, 0.f, 0.f};

    for (int dc = 0; dc < DIM; dc += 64) {
      const float* xp = x + (size_t)(tok0 + tr) * DIM + dc + d8;
      float4 a0 = *(const float4*)(xp);
      float4 a1 = *(const float4*)(xp + 4);
      xs_t[d8 + 0][tr] = a0.x; xs_t[d8 + 1][tr] = a0.y;
      xs_t[d8 + 2][tr] = a0.z; xs_t[d8 + 3][tr] = a0.w;
      xs_t[d8 + 4][tr] = a1.x; xs_t[d8 + 5][tr] = a1.y;
      xs_t[d8 + 6][tr] = a1.z; xs_t[d8 + 7][tr] = a1.w;
      const float* wp = w_sel + (size_t)tr * DIM + dc + d8;
      float4 b0 = *(const float4*)(wp);
      float4 b1 = *(const float4*)(wp + 4);
      ws[tr][d8 + 0] = b0.x; ws[tr][d8 + 1] = b0.y;
      ws[tr][d8 + 2] = b0.z; ws[tr][d8 + 3] = b0.w;
      ws[tr][d8 + 4] = b1.x; ws[tr][d8 + 5] = b1.y;
      ws[tr][d8 + 6] = b1.z; ws[tr][d8 + 7] = b1.w;
      __syncthreads();

      #pragma unroll 8
      for (int d = 0; d < 64; ++d) {
        float w = ws[tr][d];
        float4 xv = *(const float4*)&xs_t[d][tg4];
        acc[0] += xv.x * w; acc[1] += xv.y * w;
        acc[2] += xv.z * w; acc[3] += xv.w * w;
      }
      __syncthreads();
    }

    #pragma unroll
    for (int j = 0; j < 4; ++j)
      S[tg4 + j][tr] = acc[j];
    __syncthreads();

    if (tid < RT) {
      const int t = tid;
      float m1 = -1e30f, m2 = -1e30f;
      int i1 = 0, i2 = 0;
      for (int ee = 0; ee < NEXP; ++ee) {
        float v = S[t][ee];
        if (v > m1)      { m2 = m1; i2 = i1; m1 = v; i1 = ee; }
        else if (v > m2) { m2 = v; i2 = ee; }
      }
      const int token = tok0 + t;
      float g1 = 1.f / (1.f + __expf(-m1));
      float g2 = 1.f / (1.f + __expf(-m2));
      // choice 0 = top-1, choice 1 = top-2; entry = (gate_bf16<<16)|token
      int p1 = atomicAdd(&counts[i1 * 2 + 0], 1);
      if (p1 < LCAP2) list[(i1 * 2 + 0) * LCAP2 + p1] = ((unsigned)f2bf(g1) << 16) | (unsigned)token;
      int p2 = atomicAdd(&counts[i2 * 2 + 1], 1);
      if (p2 < LCAP2) list[(i2 * 2 + 1) * LCAP2 + p2] = ((unsigned)f2bf(g2) << 16) | (unsigned)token;
    }
  }
}

// ------------- FFN pass (one router choice): barrier-free K-loops ----------
// grid 1024: e = bid&31, dhalf = (bid>>5)&1, slot = bid>>6 (grid-stride).
// Phase A computes S^T (rows=h from wk_t, cols=tokens gathered from xbf) --
// all operands straight from global/L2, no LDS staging, no K-loop barriers.
// Phase B computes out^T-tiles (rows=d from wv_t, cols=tokens, K=H via LDS).
// choice==0: plain float4 stores (full token coverage); choice==1: RMW add.
__global__ __launch_bounds__(256, 2) void ffn_pass_kernel(
    const unsigned short* __restrict__ xbf,
    const unsigned short* __restrict__ wk_t,   // bf16 [E][H][D]
    const unsigned short* __restrict__ wv_t,   // bf16 [E][D][H]
    float* __restrict__ out,
    const int* __restrict__ counts, const unsigned* __restrict__ list,
    int choice)
{
  const int bid   = blockIdx.x;
  const int e     = bid & 31;
  const int dhalf = (bid >> 5) & 1;
  const int slot  = bid >> 6;               // 0..15
  const int cnt   = min(counts[e * 2 + choice], LCAP2);

  // scores S^T staged so phase-B B-frags are one ds_read_b128:
  // ss2[k>>3][token][k&7]
  __shared__ __align__(16) unsigned short ss2[16][TT][8];
  __shared__ int   toks[TT];
  __shared__ float gates[TT];

  const int tid  = threadIdx.x;
  const int wave = tid >> 6;
  const int lane = tid & 63;
  const int quad = lane >> 4;
  const int l16  = lane & 15;

  const unsigned short* wkb = wk_t + (size_t)e * NH * DIM;
  const unsigned short* wvb = wv_t + (size_t)e * DIM * NH;
  const unsigned* lst = list + (size_t)(e * 2 + choice) * LCAP2;

  for (int t0 = slot * TT; t0 < cnt; t0 += SLOTS * TT) {
    const int n_tok = min(TT, cnt - t0);
    __syncthreads();                         // prev iter's reads of toks/ss2 done
    if (tid < TT) {
      int valid = tid < n_tok;
      unsigned en = valid ? lst[t0 + tid] : 0u;
      toks[tid]  = (int)(en & 0xffffu);
      gates[tid] = valid ? bf2f((unsigned short)(en >> 16)) : 0.f;
    }
    __syncthreads();

    // ---- Phase A: S^T = relu(Wk @ X^T) * gate   (rows h=128, cols tok=32)
    // wave handles h-tiles {2w, 2w+1} x token-tiles {0,1}
    const unsigned short* xg0 = xbf + (size_t)toks[l16]      * DIM + quad * 8;
    const unsigned short* xg1 = xbf + (size_t)toks[16 + l16] * DIM + quad * 8;
    const unsigned short* wg0 = wkb + (size_t)((wave * 2 + 0) * 16 + l16) * DIM + quad * 8;
    const unsigned short* wg1 = wkb + (size_t)((wave * 2 + 1) * 16 + l16) * DIM + quad * 8;

    float4_ accA[2][2];
    #pragma unroll
    for (int i = 0; i < 2; ++i)
      #pragma unroll
      for (int j = 0; j < 2; ++j) accA[i][j] = (float4_){0.f, 0.f, 0.f, 0.f};

    #pragma unroll 8
    for (int ks = 0; ks < 32; ++ks) {
      const int off = ks * 32;
      short8 a0 = *(const short8*)(wg0 + off);
      short8 a1 = *(const short8*)(wg1 + off);
      short8 b0 = *(const short8*)(xg0 + off);
      short8 b1 = *(const short8*)(xg1 + off);
      accA[0][0] = __builtin_amdgcn_mfma_f32_16x16x32_bf16(a0, b0, accA[0][0], 0, 0, 0);
      accA[0][1] = __builtin_amdgcn_mfma_f32_16x16x32_bf16(a0, b1, accA[0][1], 0, 0, 0);
      accA[1][0] = __builtin_amdgcn_mfma_f32_16x16x32_bf16(a1, b0, accA[1][0], 0, 0, 0);
      accA[1][1] = __builtin_amdgcn_mfma_f32_16x16x32_bf16(a1, b1, accA[1][1], 0, 0, 0);
    }

    // epilogue A: relu * gate -> bf16 -> ss2 (one 8B ds_write per acc tile)
    #pragma unroll
    for (int ht = 0; ht < 2; ++ht) {
      const int hb = (wave * 2 + ht) * 2 + (quad >> 1);
      #pragma unroll
      for (int tt = 0; tt < 2; ++tt) {
        const int t = tt * 16 + l16;
        const float g = gates[t];
        short4_ w;
        #pragma unroll
        for (int r = 0; r < 4; ++r)
          w[r] = (short)f2bf(fmaxf(accA[ht][tt][r], 0.f) * g);
        *(short4_*)&ss2[hb][t][(quad & 1) * 4] = w;
      }
    }
    __syncthreads();

    // ---- Phase B: out^T-tiles = Wv^T @ S  (rows d, cols tok, K=128)
    // wave handles d-tiles dhalf*32 + wave*8 + i (i<8), both token-tiles.
    float4_ accB[8][2];
    #pragma unroll
    for (int i = 0; i < 8; ++i)
      #pragma unroll
      for (int j = 0; j < 2; ++j) accB[i][j] = (float4_){0.f, 0.f, 0.f, 0.f};

    #pragma unroll
    for (int ks = 0; ks < 4; ++ks) {
      short8 b0 = *(const short8*)&ss2[ks * 4 + quad][l16][0];
      short8 b1 = *(const short8*)&ss2[ks * 4 + quad][16 + l16][0];
      #pragma unroll
      for (int i = 0; i < 8; ++i) {
        const int d = (dhalf * 32 + wave * 8 + i) * 16 + l16;
        short8 a = *(const short8*)(wvb + (size_t)d * NH + ks * 32 + quad * 8);
        accB[i][0] = __builtin_amdgcn_mfma_f32_16x16x32_bf16(a, b0, accB[i][0], 0, 0, 0);
        accB[i][1] = __builtin_amdgcn_mfma_f32_16x16x32_bf16(a, b1, accB[i][1], 0, 0, 0);
      }
    }

    // store: lane holds 4 consecutive d for token col l16 -> float4
    #pragma unroll
    for (int tt = 0; tt < 2; ++tt) {
      const int t = tt * 16 + l16;
      if (t < n_tok) {
        float* rowp = out + (size_t)toks[t] * DIM +
                      (dhalf * 32 + wave * 8) * 16 + quad * 4;
        #pragma unroll
        for (int i = 0; i < 8; ++i) {
          float4 v;
          v.x = accB[i][tt][0]; v.y = accB[i][tt][1];
          v.z = accB[i][tt][2]; v.w = accB[i][tt][3];
          float* p = rowp + i * 16;
          if (choice) {
            float4 o = *(float4*)p;
            v.x += o.x; v.y += o.y; v.z += o.z; v.w += o.w;
          }
          *(float4*)p = v;
        }
      }
    }
  }
}

extern "C" void kernel_launch(void* const* d_in, const int* in_sizes, int n_in,
                              void* d_out, int out_size, void* d_ws, size_t ws_size,
                              hipStream_t stream) {
  (void)in_sizes; (void)n_in; (void)ws_size; (void)out_size;
  const float* x        = (const float*)d_in[0];
  const float* w_sel    = (const float*)d_in[1];
  const float* w_keys   = (const float*)d_in[2];
  const float* w_values = (const float*)d_in[3];
  float* out = (float*)d_out;

  // workspace (~33.1 MB; R4 proved >= 33.7 MB works)
  char* ws = (char*)d_ws;
  size_t off = 0;
  int*            counts = (int*)(ws + off);            off += 4096;
  unsigned*       list   = (unsigned*)(ws + off);       off += (size_t)NEXP * 2 * LCAP2 * 4; // 128 KB
  unsigned short* wk_t   = (unsigned short*)(ws + off); off += (size_t)NEXP * NH * DIM * 2;  // 8 MB
  unsigned short* wv_t   = (unsigned short*)(ws + off); off += (size_t)NEXP * NH * DIM * 2;  // 8 MB
  unsigned short* xbf    = (unsigned short*)(ws + off);                                      // 16.8 MB

  hipMemsetAsync(counts, 0, sizeof(int) * NEXP * 2, stream);

  prep_router_kernel<<<12544, 256, 0, stream>>>(w_keys, w_values, x, w_sel,
                                                wk_t, wv_t, xbf, counts, list);

  // pass 1: top-1 experts, plain stores (covers every token row exactly once)
  ffn_pass_kernel<<<NEXP * 2 * SLOTS, 256, 0, stream>>>(
      xbf, wk_t, wv_t, out, counts, list, 0);
  // pass 2: top-2 experts, race-free read-modify-write (unique token rows)
  ffn_pass_kernel<<<NEXP * 2 * SLOTS, 256, 0, stream>>>(
      xbf, wk_t, wv_t, out, counts, list, 1);
}